// Round 1
// baseline (2877.465 us; speedup 1.0000x reference)
//
#include <hip/hip_runtime.h>
#include <math.h>

#define NB 4
#define GH 64
#define GW 64
#define DM 128
#define MW 256
#define NF 10
#define NPTS 65536
#define ENCD 42     // 2 + 4*NF
#define IN0 170     // ENCD + DM
#define TT 32       // points per workgroup tile
#define TPB 256

__device__ __forceinline__ float gelu_f(float x) {
  // jax.nn.gelu default: approximate=True (tanh form)
  const float c0 = 0.7978845608028654f;  // sqrt(2/pi)
  float inner = c0 * (x + 0.044715f * x * x * x);
  return 0.5f * x * (1.0f + tanhf(inner));
}

// ctx (4,128) @ w_film (128,512) + b_film -> filmout (4,512)
__global__ void film_kernel(const float* __restrict__ ctx,
                            const float* __restrict__ wf,
                            const float* __restrict__ bf,
                            float* __restrict__ filmout) {
  const int b = blockIdx.x;
  const int j = threadIdx.x;  // 0..511
  float acc = bf[j];
  for (int k = 0; k < DM; ++k)
    acc = fmaf(ctx[b * DM + k], wf[k * 512 + j], acc);
  filmout[b * 512 + j] = acc;
}

// One MLP layer: hout[t][tid] = gelu( (hin[t][:] . w[:,tid] + bias)*g1 + bt )
__device__ __forceinline__ void mlp_layer(const float (*__restrict__ hin)[MW],
                                          float (*__restrict__ hout)[MW],
                                          const float* __restrict__ w,
                                          float bias, int K, float g1, float bt,
                                          int tid) {
  float acc[TT];
#pragma unroll
  for (int t = 0; t < TT; ++t) acc[t] = bias;
  int k = 0;
  for (; k + 4 <= K; k += 4) {
    const float wa = w[(k + 0) * MW + tid];
    const float wb = w[(k + 1) * MW + tid];
    const float wc = w[(k + 2) * MW + tid];
    const float wd = w[(k + 3) * MW + tid];
#pragma unroll
    for (int t = 0; t < TT; ++t) {
      const float4 h4 = *(const float4*)(&hin[t][k]);  // LDS broadcast, 16B aligned
      acc[t] = fmaf(h4.x, wa, acc[t]);
      acc[t] = fmaf(h4.y, wb, acc[t]);
      acc[t] = fmaf(h4.z, wc, acc[t]);
      acc[t] = fmaf(h4.w, wd, acc[t]);
    }
  }
  for (; k < K; ++k) {  // remainder (K=170 case)
    const float wv = w[k * MW + tid];
#pragma unroll
    for (int t = 0; t < TT; ++t) acc[t] = fmaf(hin[t][k], wv, acc[t]);
  }
#pragma unroll
  for (int t = 0; t < TT; ++t) {
    const float v = fmaf(acc[t], g1, bt);  // FiLM: h*(gamma+1)+beta
    hout[t][tid] = gelu_f(v);              // consecutive tid -> conflict-free
  }
}

__global__ __launch_bounds__(TPB) void decoder_kernel(
    const float* __restrict__ grid, const float* __restrict__ coords,
    const float* __restrict__ w0, const float* __restrict__ b0,
    const float* __restrict__ w1, const float* __restrict__ b1,
    const float* __restrict__ w2, const float* __restrict__ b2,
    const float* __restrict__ w3, const float* __restrict__ b3,
    const float* __restrict__ wo, const float* __restrict__ bo,
    const float* __restrict__ film, float* __restrict__ out) {
  __shared__ float hbuf[2][TT][MW];  // exactly 64 KiB
  const int tid = threadIdx.x;
  const int tilesPerB = NPTS / TT;  // 2048
  const int b = blockIdx.x / tilesPerB;
  const int n0 = (blockIdx.x % tilesPerB) * TT;

  // phase 1a: positional encoding (cols: x,y, then per freq sinx,siny,cosx,cosy)
  if (tid < TT) {
    const int t = tid;
    const float x = coords[(size_t)(n0 + t) * 2 + 0];
    const float y = coords[(size_t)(n0 + t) * 2 + 1];
    hbuf[0][t][0] = x;
    hbuf[0][t][1] = y;
    float fr = 3.14159265358979323846f;  // pi * 2^0
#pragma unroll
    for (int i = 0; i < NF; ++i) {
      hbuf[0][t][2 + 4 * i + 0] = sinf(x * fr);
      hbuf[0][t][2 + 4 * i + 1] = sinf(y * fr);
      hbuf[0][t][2 + 4 * i + 2] = cosf(x * fr);
      hbuf[0][t][2 + 4 * i + 3] = cosf(y * fr);
      fr *= 2.0f;
    }
  }
  __syncthreads();

  // phase 1b: bilinear sample of feature grid (in-range coords; clamps defensive)
  for (int idx = tid; idx < TT * DM; idx += TPB) {
    const int t = idx >> 7;          // / DM
    const int c = idx & (DM - 1);
    const float x = coords[(size_t)(n0 + t) * 2 + 0];
    const float y = coords[(size_t)(n0 + t) * 2 + 1];
    const float cr = (x + 1.0f) * 0.5f * 63.0f;  // row (H axis)
    const float cc = (y + 1.0f) * 0.5f * 63.0f;  // col (W axis)
    int r0 = (int)floorf(cr);
    int q0 = (int)floorf(cc);
    const float frr = cr - (float)r0;
    const float frc = cc - (float)q0;
    r0 = max(0, min(r0, GH - 1));
    q0 = max(0, min(q0, GW - 1));
    const int r1 = min(r0 + 1, GH - 1);
    const int q1 = min(q0 + 1, GW - 1);
    const float* gb = grid + (size_t)b * (GH * GW * DM);
    const float v00 = gb[(r0 * GW + q0) * DM + c];
    const float v01 = gb[(r0 * GW + q1) * DM + c];
    const float v10 = gb[(r1 * GW + q0) * DM + c];
    const float v11 = gb[(r1 * GW + q1) * DM + c];
    const float vtop = v00 + (v01 - v00) * frc;
    const float vbot = v10 + (v11 - v10) * frc;
    hbuf[0][t][ENCD + c] = vtop + (vbot - vtop) * frr;
  }

  const float g1 = film[b * 512 + tid] + 1.0f;       // gamma + 1
  const float bt = film[b * 512 + MW + tid];         // beta
  __syncthreads();

  mlp_layer(hbuf[0], hbuf[1], w0, b0[tid], IN0, g1, bt, tid);
  __syncthreads();
  mlp_layer(hbuf[1], hbuf[0], w1, b1[tid], MW, g1, bt, tid);
  __syncthreads();
  mlp_layer(hbuf[0], hbuf[1], w2, b2[tid], MW, g1, bt, tid);
  __syncthreads();
  mlp_layer(hbuf[1], hbuf[0], w3, b3[tid], MW, g1, bt, tid);
  __syncthreads();

  // output layer: 256 -> 3, 8 lanes per point, shuffle-reduce, tanh
  {
    const int t = tid >> 3;
    const int r = tid & 7;
    const int kb = r * 32;
    float p0 = 0.f, p1 = 0.f, p2 = 0.f;
#pragma unroll
    for (int kk = 0; kk < 32; ++kk) {
      const float hv = hbuf[0][t][kb + kk];
      p0 = fmaf(hv, wo[(kb + kk) * 3 + 0], p0);
      p1 = fmaf(hv, wo[(kb + kk) * 3 + 1], p1);
      p2 = fmaf(hv, wo[(kb + kk) * 3 + 2], p2);
    }
#pragma unroll
    for (int m = 1; m < 8; m <<= 1) {
      p0 += __shfl_xor(p0, m, 64);
      p1 += __shfl_xor(p1, m, 64);
      p2 += __shfl_xor(p2, m, 64);
    }
    if (r == 0) {
      const size_t o = ((size_t)b * NPTS + n0 + t) * 3;
      out[o + 0] = tanhf(p0 + bo[0]);
      out[o + 1] = tanhf(p1 + bo[1]);
      out[o + 2] = tanhf(p2 + bo[2]);
    }
  }
}

extern "C" void kernel_launch(void* const* d_in, const int* in_sizes, int n_in,
                              void* d_out, int out_size, void* d_ws, size_t ws_size,
                              hipStream_t stream) {
  const float* grid   = (const float*)d_in[0];
  const float* ctx    = (const float*)d_in[1];
  const float* coords = (const float*)d_in[2];
  const float* w0 = (const float*)d_in[3];
  const float* b0 = (const float*)d_in[4];
  const float* w1 = (const float*)d_in[5];
  const float* b1 = (const float*)d_in[6];
  const float* w2 = (const float*)d_in[7];
  const float* b2 = (const float*)d_in[8];
  const float* w3 = (const float*)d_in[9];
  const float* b3 = (const float*)d_in[10];
  const float* wf = (const float*)d_in[11];
  const float* bf = (const float*)d_in[12];
  const float* wo = (const float*)d_in[13];
  const float* bo = (const float*)d_in[14];
  float* out = (float*)d_out;
  float* filmbuf = (float*)d_ws;  // 4*512 floats = 8 KiB scratch

  hipLaunchKernelGGL(film_kernel, dim3(NB), dim3(512), 0, stream, ctx, wf, bf, filmbuf);
  hipLaunchKernelGGL(decoder_kernel, dim3(NB * (NPTS / TT)), dim3(TPB), 0, stream,
                     grid, coords, w0, b0, w1, b1, w2, b2, w3, b3, wo, bo,
                     filmbuf, out);
}

// Round 2
// 368.983 us; speedup vs baseline: 7.7984x; 7.7984x over previous
//
#include <hip/hip_runtime.h>
#include <math.h>

#define NB 4
#define GH 64
#define GW 64
#define DM 128
#define MW 256
#define NF 10
#define NPTS 65536
#define ENCD 42
#define K0P 192        // layer0 K padded 170 -> 192
#define MT 64          // points per block
#define TPB 256
#define LDK 264        // act row stride in f16 (diagonal-ish banks, 16B aligned)

typedef _Float16 f16x8 __attribute__((ext_vector_type(8)));
typedef float f32x4 __attribute__((ext_vector_type(4)));

// d_ws layout: [0, 8192) film fp32 (4x512); [8192, ...) packed f16 weights.
// kt-unit = one K=32 slab of one layer = 16 ntiles * 64 lanes * 8 f16 = 8192 halves.
#define KTU 8192
#define KT0 0    // layer0: 6 units (K=192)
#define KT1 6    // layers 1-3: 8 units each
#define KT2 14
#define KT3 22
#define KT_TOTAL 30

__device__ __forceinline__ float gelu_f(float x) {
  // jax.nn.gelu approximate=True: 0.5x(1+tanh(sqrt(2/pi)(x+0.044715x^3)))
  float z = 0.7978845608028654f * fmaf(0.044715f * x, x * x, x);
  float e = __expf(2.0f * z);              // overflow->inf->t=1; underflow->0->t=-1
  float t = 1.0f - 2.0f / (e + 1.0f);
  return 0.5f * x * (1.0f + t);
}

// ctx (4,128) @ w_film (128,512) + b_film -> film (4,512) fp32
__global__ void film_kernel(const float* __restrict__ ctx,
                            const float* __restrict__ wf,
                            const float* __restrict__ bf,
                            float* __restrict__ filmout) {
  const int b = blockIdx.x;
  const int j = threadIdx.x;
  float acc = bf[j];
  for (int k = 0; k < DM; ++k)
    acc = fmaf(ctx[b * DM + k], wf[k * 512 + j], acc);
  filmout[b * 512 + j] = acc;
}

// Pack W (K x 256 fp32) into MFMA B-fragment order, f16:
// dst[((ktg*16+nt)*64+lane)*8 + j] = W[kt*32 + (lane>>4)*8 + j][nt*16 + (lane&15)]
__global__ void pack_kernel(const float* __restrict__ w0, const float* __restrict__ w1,
                            const float* __restrict__ w2, const float* __restrict__ w3,
                            _Float16* __restrict__ wp) {
  const int u = blockIdx.x * 256 + threadIdx.x;
  if (u >= KT_TOTAL * 16 * 64) return;
  const int lane = u & 63;
  const int v = u >> 6;
  const int nt = v & 15;
  const int ktg = v >> 4;  // 0..29
  const float* w; int ktl, K;
  if (ktg < KT1)      { w = w0; ktl = ktg - KT0; K = 170; }
  else if (ktg < KT2) { w = w1; ktl = ktg - KT1; K = 256; }
  else if (ktg < KT3) { w = w2; ktl = ktg - KT2; K = 256; }
  else                { w = w3; ktl = ktg - KT3; K = 256; }
  const int n = nt * 16 + (lane & 15);
  const int kbase = ktl * 32 + (lane >> 4) * 8;
  _Float16* dst = wp + (size_t)u * 8;
#pragma unroll
  for (int j = 0; j < 8; ++j) {
    const int k = kbase + j;
    dst[j] = (_Float16)((k < K) ? w[k * MW + n] : 0.0f);
  }
}

__global__ __launch_bounds__(TPB, 4) void decoder_kernel(
    const float* __restrict__ grid, const float* __restrict__ coords,
    const float* __restrict__ b0, const float* __restrict__ b1,
    const float* __restrict__ b2, const float* __restrict__ b3,
    const float* __restrict__ wo, const float* __restrict__ bo,
    const float* __restrict__ film, const _Float16* __restrict__ wpack,
    float* __restrict__ out) {
  __shared__ _Float16 act[MT * LDK];     // 33792 B
  __shared__ float wolds[MW * 3 + 4];    // 3088 B (w_out staged + bias)
  __shared__ float cco[MT][4];           // 1024 B (per-point bilinear setup)

  const int tid = threadIdx.x;
  const int lane = tid & 63;
  const int wc = tid >> 6;                 // wave id 0..3 = n-col block
  const int b = blockIdx.x >> 10;          // 1024 tiles per batch
  const int n0 = (blockIdx.x & 1023) * MT;

  // ---- stage w_out/b_out into LDS ----
  for (int i = tid; i < MW * 3 + 3; i += TPB)
    wolds[i] = (i < MW * 3) ? wo[i] : bo[i - MW * 3];

  // ---- per-point bilinear setup ----
  if (tid < MT) {
    const float x = coords[(size_t)(n0 + tid) * 2 + 0];
    const float y = coords[(size_t)(n0 + tid) * 2 + 1];
    const float cr = (x + 1.0f) * 0.5f * 63.0f;
    const float cc = (y + 1.0f) * 0.5f * 63.0f;
    const float r0f = floorf(cr), q0f = floorf(cc);
    int r0 = min(max((int)r0f, 0), GH - 1);
    int q0 = min(max((int)q0f, 0), GW - 1);
    cco[tid][0] = __int_as_float(r0);
    cco[tid][1] = __int_as_float(q0);
    cco[tid][2] = cr - r0f;
    cco[tid][3] = cc - q0f;
  }

  // ---- positional encoding + zero-pad cols 170..191 ----
  {
    const int p = tid & 63;
    const int j = tid >> 6;  // 0..3
    const float x = coords[(size_t)(n0 + p) * 2 + 0];
    const float y = coords[(size_t)(n0 + p) * 2 + 1];
    _Float16* row = act + p * LDK;
    if (j == 0) { row[0] = (_Float16)x; row[1] = (_Float16)y; }
    if (j == 1) {
      for (int c = ENCD + DM; c < K0P; ++c) row[c] = (_Float16)0.0f;
    }
    for (int i = j; i < NF; i += 4) {
      const float fr = 3.14159265358979323846f * (float)(1 << i);
      row[2 + 4 * i + 0] = (_Float16)sinf(x * fr);
      row[2 + 4 * i + 1] = (_Float16)sinf(y * fr);
      row[2 + 4 * i + 2] = (_Float16)cosf(x * fr);
      row[2 + 4 * i + 3] = (_Float16)cosf(y * fr);
    }
  }
  __syncthreads();

  // ---- bilinear sampling: cols 42..169 ----
  {
    const float* gb = grid + (size_t)b * (GH * GW * DM);
#pragma unroll 4
    for (int it = 0; it < (MT * DM) / TPB; ++it) {
      const int idx = it * TPB + tid;
      const int p = idx >> 7;
      const int c = idx & (DM - 1);
      const int r0 = __float_as_int(cco[p][0]);
      const int q0 = __float_as_int(cco[p][1]);
      const float frr = cco[p][2], frc = cco[p][3];
      const int r1 = min(r0 + 1, GH - 1), q1 = min(q0 + 1, GW - 1);
      const float* base0 = gb + (size_t)(r0 * GW) * DM + c;
      const float* base1 = gb + (size_t)(r1 * GW) * DM + c;
      const float v00 = base0[q0 * DM], v01 = base0[q1 * DM];
      const float v10 = base1[q0 * DM], v11 = base1[q1 * DM];
      const float vt = v00 + (v01 - v00) * frc;
      const float vb = v10 + (v11 - v10) * frc;
      act[p * LDK + ENCD + c] = (_Float16)(vt + (vb - vt) * frr);
    }
  }

  // ---- FiLM params for this wave's columns (fixed across layers) ----
  const int colbase = wc * 64 + (lane & 15);
  float g1[4], bt[4];
#pragma unroll
  for (int nt = 0; nt < 4; ++nt) {
    g1[nt] = film[b * 512 + colbase + nt * 16] + 1.0f;
    bt[nt] = film[b * 512 + MW + colbase + nt * 16];
  }
  __syncthreads();

  // ---- fused MLP layers ----
  auto run_layer = [&](const _Float16* __restrict__ wl,
                       const float* __restrict__ bl, const int Kt) {
    f32x4 acc[4][4];
#pragma unroll
    for (int mt = 0; mt < 4; ++mt)
#pragma unroll
      for (int nt = 0; nt < 4; ++nt)
        acc[mt][nt] = (f32x4){0.f, 0.f, 0.f, 0.f};

    const int arow = lane & 15;
    const int kq = (lane >> 4) * 8;
#pragma unroll 2
    for (int kt = 0; kt < Kt; ++kt) {
      f16x8 bfr[4];
#pragma unroll
      for (int nt = 0; nt < 4; ++nt)
        bfr[nt] = *(const f16x8*)(wl + ((size_t)((kt * 16 + wc * 4 + nt) * 64 + lane)) * 8);
      f16x8 afr[4];
      const int kof = kt * 32 + kq;
#pragma unroll
      for (int mt = 0; mt < 4; ++mt)
        afr[mt] = *(const f16x8*)(act + (mt * 16 + arow) * LDK + kof);
#pragma unroll
      for (int mt = 0; mt < 4; ++mt)
#pragma unroll
        for (int nt = 0; nt < 4; ++nt)
          acc[mt][nt] = __builtin_amdgcn_mfma_f32_16x16x32_f16(afr[mt], bfr[nt], acc[mt][nt], 0, 0, 0);
    }
    __syncthreads();  // all waves done reading act
    // epilogue: bias + FiLM + GELU -> f16 back into act (C/D: col=lane&15, row=(lane>>4)*4+r)
#pragma unroll
    for (int nt = 0; nt < 4; ++nt) {
      const float bb = bl[colbase + nt * 16];
      const int col = wc * 64 + nt * 16 + (lane & 15);
#pragma unroll
      for (int mt = 0; mt < 4; ++mt) {
        const int rowb = mt * 16 + (lane >> 4) * 4;
#pragma unroll
        for (int r = 0; r < 4; ++r) {
          const float v = (acc[mt][nt][r] + bb) * g1[nt] + bt[nt];
          act[(rowb + r) * LDK + col] = (_Float16)gelu_f(v);
        }
      }
    }
    __syncthreads();
  };

  run_layer(wpack + (size_t)KT0 * KTU, b0, 6);
  run_layer(wpack + (size_t)KT1 * KTU, b1, 8);
  run_layer(wpack + (size_t)KT2 * KTU, b2, 8);
  run_layer(wpack + (size_t)KT3 * KTU, b3, 8);

  // ---- output layer 256->3 + tanh (4 lanes per point, shuffle-reduce) ----
  {
    const int p = tid >> 2;     // 0..63
    const int r = tid & 3;
    const int k0 = r * 64;
    float p0 = 0.f, p1 = 0.f, p2 = 0.f;
#pragma unroll
    for (int jj = 0; jj < 64; jj += 8) {
      const f16x8 h8 = *(const f16x8*)(act + p * LDK + k0 + jj);
#pragma unroll
      for (int e = 0; e < 8; ++e) {
        const float hv = (float)h8[e];
        const float* w3 = &wolds[(k0 + jj + e) * 3];
        p0 = fmaf(hv, w3[0], p0);
        p1 = fmaf(hv, w3[1], p1);
        p2 = fmaf(hv, w3[2], p2);
      }
    }
    p0 += __shfl_xor(p0, 1, 64); p0 += __shfl_xor(p0, 2, 64);
    p1 += __shfl_xor(p1, 1, 64); p1 += __shfl_xor(p1, 2, 64);
    p2 += __shfl_xor(p2, 1, 64); p2 += __shfl_xor(p2, 2, 64);
    if (r == 0) {
      const size_t o = ((size_t)b * NPTS + n0 + p) * 3;
      out[o + 0] = tanhf(p0 + wolds[MW * 3 + 0]);
      out[o + 1] = tanhf(p1 + wolds[MW * 3 + 1]);
      out[o + 2] = tanhf(p2 + wolds[MW * 3 + 2]);
    }
  }
}

extern "C" void kernel_launch(void* const* d_in, const int* in_sizes, int n_in,
                              void* d_out, int out_size, void* d_ws, size_t ws_size,
                              hipStream_t stream) {
  const float* grid   = (const float*)d_in[0];
  const float* ctx    = (const float*)d_in[1];
  const float* coords = (const float*)d_in[2];
  const float* w0 = (const float*)d_in[3];
  const float* b0 = (const float*)d_in[4];
  const float* w1 = (const float*)d_in[5];
  const float* b1 = (const float*)d_in[6];
  const float* w2 = (const float*)d_in[7];
  const float* b2 = (const float*)d_in[8];
  const float* w3 = (const float*)d_in[9];
  const float* b3 = (const float*)d_in[10];
  const float* wf = (const float*)d_in[11];
  const float* bf = (const float*)d_in[12];
  const float* wo = (const float*)d_in[13];
  const float* bo = (const float*)d_in[14];
  float* out = (float*)d_out;

  float* filmbuf = (float*)d_ws;                       // 8 KiB
  _Float16* wpack = (_Float16*)((char*)d_ws + 8192);   // ~480 KiB

  hipLaunchKernelGGL(film_kernel, dim3(NB), dim3(512), 0, stream, ctx, wf, bf, filmbuf);
  hipLaunchKernelGGL(pack_kernel, dim3((KT_TOTAL * 16 * 64 + 255) / 256), dim3(256), 0, stream,
                     w0, w1, w2, w3, wpack);
  hipLaunchKernelGGL(decoder_kernel, dim3(NB * (NPTS / MT)), dim3(TPB), 0, stream,
                     grid, coords, b0, b1, b2, b3, wo, bo, filmbuf, wpack, out);
}

// Round 4
// 279.436 us; speedup vs baseline: 10.2974x; 1.3205x over previous
//
#include <hip/hip_runtime.h>
#include <math.h>

#define NB 4
#define GH 64
#define GW 64
#define DM 128
#define MW 256
#define NF 10
#define NPTS 65536
#define ENCD 42
#define MT 64          // points per block
#define TPB 256
#define LDK 264        // act row stride in f16

typedef _Float16 f16x8 __attribute__((ext_vector_type(8)));
typedef __fp16 h16x2 __attribute__((ext_vector_type(2)));   // cvt_pkrtz return type
typedef float f32x4 __attribute__((ext_vector_type(4)));

// d_ws: [0,8192) film fp32 (4x512); [8192,...) packed f16 weights.
// unit = 64 lanes x 8 halves. Main layers: ktg 0..29 x 16 n-tiles. Then w_out: 8 kt units.
#define KTU 8192       // halves per K=32 slab (16 ntiles * 64 * 8)
#define KT0 0
#define KT1 6
#define KT2 14
#define KT3 22
#define KT_TOTAL 30
#define NUNIT_MAIN (KT_TOTAL * 16 * 64)   // 30720 unit-rows
#define OUT_OFF ((size_t)NUNIT_MAIN * 8)  // halves offset of w_out pack

__device__ __forceinline__ float gelu_fast(float v) {
  // v * sigmoid(2*sqrt(2/pi)*(v+0.044715 v^3)) via exp2+rcp (no div)
  const float t = v * v;
  const float w = fmaf(-0.10294324f, t, -2.3022082f);   // -2*log2e*c0*(1, 0.044715)
  const float e = __builtin_amdgcn_exp2f(v * w);
  return v * __builtin_amdgcn_rcpf(1.0f + e);
}

__device__ __forceinline__ float tanh_fast(float v) {
  const float e = __builtin_amdgcn_exp2f(2.8853900818f * v);  // e^(2v)
  return 1.0f - 2.0f * __builtin_amdgcn_rcpf(1.0f + e);
}

// ctx (4,128) @ w_film (128,512) + b_film -> film (4,512) fp32
__global__ void film_kernel(const float* __restrict__ ctx,
                            const float* __restrict__ wf,
                            const float* __restrict__ bf,
                            float* __restrict__ filmout) {
  const int b = blockIdx.x;
  const int j = threadIdx.x;
  float acc = bf[j];
  for (int k = 0; k < DM; ++k)
    acc = fmaf(ctx[b * DM + k], wf[k * 512 + j], acc);
  filmout[b * 512 + j] = acc;
}

// Pack weights into MFMA B-fragment order (f16).
__global__ void pack_kernel(const float* __restrict__ w0, const float* __restrict__ w1,
                            const float* __restrict__ w2, const float* __restrict__ w3,
                            const float* __restrict__ wo, _Float16* __restrict__ wp) {
  const int u = blockIdx.x * 256 + threadIdx.x;
  const int lane = u & 63;
  if (u < NUNIT_MAIN) {
    const int v = u >> 6;
    const int nt = v & 15;
    const int ktg = v >> 4;
    const float* w; int ktl, K;
    if (ktg < KT1)      { w = w0; ktl = ktg - KT0; K = 170; }
    else if (ktg < KT2) { w = w1; ktl = ktg - KT1; K = 256; }
    else if (ktg < KT3) { w = w2; ktl = ktg - KT2; K = 256; }
    else                { w = w3; ktl = ktg - KT3; K = 256; }
    const int n = nt * 16 + (lane & 15);
    const int kbase = ktl * 32 + (lane >> 4) * 8;
    _Float16* dst = wp + (size_t)u * 8;
#pragma unroll
    for (int j = 0; j < 8; ++j) {
      const int k = kbase + j;
      dst[j] = (_Float16)((k < K) ? w[k * MW + n] : 0.0f);
    }
  } else if (u < NUNIT_MAIN + 8 * 64) {
    // w_out (256 x 3) -> B-frag with N padded to 16
    const int kt = (u - NUNIT_MAIN) >> 6;
    const int col = lane & 15;
    const int kbase = kt * 32 + (lane >> 4) * 8;
    _Float16* dst = wp + (size_t)u * 8;
#pragma unroll
    for (int j = 0; j < 8; ++j)
      dst[j] = (_Float16)((col < 3) ? wo[(kbase + j) * 3 + col] : 0.0f);
  }
}

__global__ __launch_bounds__(TPB, 4) void decoder_kernel(
    const float* __restrict__ grid, const float* __restrict__ coords,
    const float* __restrict__ b0, const float* __restrict__ b1,
    const float* __restrict__ b2, const float* __restrict__ b3,
    const float* __restrict__ bo,
    const float* __restrict__ film, const _Float16* __restrict__ wpack,
    float* __restrict__ out) {
  __shared__ _Float16 act[MT * LDK];   // 33792 B
  __shared__ float4 cco4[MT];          // 1024 B

  const int tid = threadIdx.x;
  const int lane = tid & 63;
  const int wc = tid >> 6;
  const int b = blockIdx.x >> 10;
  const int n0 = (blockIdx.x & 1023) * MT;

  // ---- per-point bilinear setup ----
  if (tid < MT) {
    const float x = coords[(size_t)(n0 + tid) * 2 + 0];
    const float y = coords[(size_t)(n0 + tid) * 2 + 1];
    const float cr = (x + 1.0f) * 0.5f * 63.0f;
    const float cc = (y + 1.0f) * 0.5f * 63.0f;
    const float r0f = floorf(cr), q0f = floorf(cc);
    const int r0 = min(max((int)r0f, 0), GH - 1);
    const int q0 = min(max((int)q0f, 0), GW - 1);
    float4 v;
    v.x = __int_as_float(r0);
    v.y = __int_as_float(q0);
    v.z = cr - r0f;
    v.w = cc - q0f;
    cco4[tid] = v;
  }

  // ---- positional encoding via hw sin/cos (revolutions) + zero-pad 170..191 ----
  {
    const int p = tid & 63;
    const int j = tid >> 6;
    const float x = coords[(size_t)(n0 + p) * 2 + 0];
    const float y = coords[(size_t)(n0 + p) * 2 + 1];
    _Float16* row = act + p * LDK;
    if (j == 0) { row[0] = (_Float16)x; row[1] = (_Float16)y; }
    if (j == 1) {
      for (int c = ENCD + DM; c < ENCD + DM + 22; ++c) row[c] = (_Float16)0.0f;
    }
    for (int i = j; i < NF; i += 4) {
      const float sc = 0.5f * (float)(1 << i);      // 2^(i-1): x*pi*2^i rad == x*2^(i-1) rev
      const float rx = x * sc, ry = y * sc;
      const float fx = rx - floorf(rx);
      const float fy = ry - floorf(ry);
      row[2 + 4 * i + 0] = (_Float16)__builtin_amdgcn_sinf(fx);
      row[2 + 4 * i + 1] = (_Float16)__builtin_amdgcn_sinf(fy);
      row[2 + 4 * i + 2] = (_Float16)__builtin_amdgcn_cosf(fx);
      row[2 + 4 * i + 3] = (_Float16)__builtin_amdgcn_cosf(fy);
    }
  }
  __syncthreads();

  // ---- bilinear sampling, 4 channels per thread-iter ----
  {
    const float* gb = grid + (size_t)b * (GH * GW * DM);
#pragma unroll
    for (int it = 0; it < (MT * DM / 4) / TPB; ++it) {  // 8 iters
      const int idx = it * TPB + tid;
      const int p = idx >> 5;
      const int c = (idx & 31) * 4;
      const float4 cc4 = cco4[p];
      const int r0 = __float_as_int(cc4.x);
      const int q0 = __float_as_int(cc4.y);
      const float frr = cc4.z, frc = cc4.w;
      const int r1 = min(r0 + 1, GH - 1), q1 = min(q0 + 1, GW - 1);
      const float4 v00 = *(const float4*)(gb + (size_t)(r0 * GW + q0) * DM + c);
      const float4 v01 = *(const float4*)(gb + (size_t)(r0 * GW + q1) * DM + c);
      const float4 v10 = *(const float4*)(gb + (size_t)(r1 * GW + q0) * DM + c);
      const float4 v11 = *(const float4*)(gb + (size_t)(r1 * GW + q1) * DM + c);
      float4 vt, vb, vv;
      vt.x = fmaf(v01.x - v00.x, frc, v00.x);
      vt.y = fmaf(v01.y - v00.y, frc, v00.y);
      vt.z = fmaf(v01.z - v00.z, frc, v00.z);
      vt.w = fmaf(v01.w - v00.w, frc, v00.w);
      vb.x = fmaf(v11.x - v10.x, frc, v10.x);
      vb.y = fmaf(v11.y - v10.y, frc, v10.y);
      vb.z = fmaf(v11.z - v10.z, frc, v10.z);
      vb.w = fmaf(v11.w - v10.w, frc, v10.w);
      vv.x = fmaf(vb.x - vt.x, frr, vt.x);
      vv.y = fmaf(vb.y - vt.y, frr, vt.y);
      vv.z = fmaf(vb.z - vt.z, frr, vt.z);
      vv.w = fmaf(vb.w - vt.w, frr, vt.w);
      const h16x2 lo = __builtin_amdgcn_cvt_pkrtz(vv.x, vv.y);
      const h16x2 hi = __builtin_amdgcn_cvt_pkrtz(vv.z, vv.w);
      *(h16x2*)(act + p * LDK + ENCD + c) = lo;
      *(h16x2*)(act + p * LDK + ENCD + c + 2) = hi;
    }
  }

  // ---- FiLM params for this wave's columns ----
  const int colbase = wc * 64 + (lane & 15);
  float g1[4], btv[4];
#pragma unroll
  for (int nt = 0; nt < 4; ++nt) {
    g1[nt] = film[b * 512 + colbase + nt * 16] + 1.0f;
    btv[nt] = film[b * 512 + MW + colbase + nt * 16];
  }
  __syncthreads();

  const int arow = lane & 15;
  const int kq = (lane >> 4) * 8;

  // ---- fused MLP layers ----
  auto run_layer = [&](const _Float16* __restrict__ wl,
                       const float* __restrict__ bl, const int Kt) {
    f32x4 acc[4][4];
#pragma unroll
    for (int mt = 0; mt < 4; ++mt)
#pragma unroll
      for (int nt = 0; nt < 4; ++nt)
        acc[mt][nt] = (f32x4){0.f, 0.f, 0.f, 0.f};

    float cb[4];
#pragma unroll
    for (int nt = 0; nt < 4; ++nt)
      cb[nt] = fmaf(bl[colbase + nt * 16], g1[nt], btv[nt]);  // fold bias into FiLM

#pragma unroll 2
    for (int kt = 0; kt < Kt; ++kt) {
      f16x8 bfr[4];
#pragma unroll
      for (int nt = 0; nt < 4; ++nt)
        bfr[nt] = *(const f16x8*)(wl + ((size_t)((kt * 16 + wc * 4 + nt) * 64 + lane)) * 8);
      f16x8 afr[4];
      const int kof = kt * 32 + kq;
#pragma unroll
      for (int mt = 0; mt < 4; ++mt)
        afr[mt] = *(const f16x8*)(act + (mt * 16 + arow) * LDK + kof);
#pragma unroll
      for (int mt = 0; mt < 4; ++mt)
#pragma unroll
        for (int nt = 0; nt < 4; ++nt)
          acc[mt][nt] = __builtin_amdgcn_mfma_f32_16x16x32_f16(afr[mt], bfr[nt], acc[mt][nt], 0, 0, 0);
    }
    __syncthreads();
#pragma unroll
    for (int nt = 0; nt < 4; ++nt) {
      const int col = wc * 64 + nt * 16 + (lane & 15);
#pragma unroll
      for (int mt = 0; mt < 4; ++mt) {
        const int rowb = mt * 16 + (lane >> 4) * 4;
#pragma unroll
        for (int r = 0; r < 4; ++r) {
          const float v = fmaf(acc[mt][nt][r], g1[nt], cb[nt]);
          act[(rowb + r) * LDK + col] = (_Float16)gelu_fast(v);
        }
      }
    }
    __syncthreads();
  };

  run_layer(wpack + (size_t)KT0 * KTU, b0, 6);
  run_layer(wpack + (size_t)KT1 * KTU, b1, 8);
  run_layer(wpack + (size_t)KT2 * KTU, b2, 8);
  run_layer(wpack + (size_t)KT3 * KTU, b3, 8);

  // ---- output layer via MFMA (N padded to 16, cols 3..15 zero) ----
  {
    f32x4 oacc = (f32x4){0.f, 0.f, 0.f, 0.f};
    const _Float16* wob = wpack + OUT_OFF;
#pragma unroll
    for (int kt = 0; kt < 8; ++kt) {
      const f16x8 bfr = *(const f16x8*)(wob + (size_t)(kt * 64 + lane) * 8);
      const f16x8 afr = *(const f16x8*)(act + (wc * 16 + arow) * LDK + kt * 32 + kq);
      oacc = __builtin_amdgcn_mfma_f32_16x16x32_f16(afr, bfr, oacc, 0, 0, 0);
    }
    const int col = lane & 15;
    if (col < 3) {
      const float bv = bo[col];
      const int rowb = wc * 16 + (lane >> 4) * 4;
#pragma unroll
      for (int r = 0; r < 4; ++r)
        out[((size_t)b * NPTS + n0 + rowb + r) * 3 + col] = tanh_fast(oacc[r] + bv);
    }
  }
}

extern "C" void kernel_launch(void* const* d_in, const int* in_sizes, int n_in,
                              void* d_out, int out_size, void* d_ws, size_t ws_size,
                              hipStream_t stream) {
  const float* grid   = (const float*)d_in[0];
  const float* ctx    = (const float*)d_in[1];
  const float* coords = (const float*)d_in[2];
  const float* w0 = (const float*)d_in[3];
  const float* b0 = (const float*)d_in[4];
  const float* w1 = (const float*)d_in[5];
  const float* b1 = (const float*)d_in[6];
  const float* w2 = (const float*)d_in[7];
  const float* b2 = (const float*)d_in[8];
  const float* w3 = (const float*)d_in[9];
  const float* b3 = (const float*)d_in[10];
  const float* wf = (const float*)d_in[11];
  const float* bf = (const float*)d_in[12];
  const float* wo = (const float*)d_in[13];
  const float* bo = (const float*)d_in[14];
  float* out = (float*)d_out;

  float* filmbuf = (float*)d_ws;
  _Float16* wpack = (_Float16*)((char*)d_ws + 8192);

  hipLaunchKernelGGL(film_kernel, dim3(NB), dim3(512), 0, stream, ctx, wf, bf, filmbuf);
  const int nthread = NUNIT_MAIN + 8 * 64;
  hipLaunchKernelGGL(pack_kernel, dim3((nthread + 255) / 256), dim3(256), 0, stream,
                     w0, w1, w2, w3, wo, wpack);
  hipLaunchKernelGGL(decoder_kernel, dim3(NB * (NPTS / MT)), dim3(TPB), 0, stream,
                     grid, coords, b0, b1, b2, b3, bo, filmbuf, wpack, out);
}